// Round 4
// baseline (570.256 us; speedup 1.0000x reference)
//
#include <hip/hip_runtime.h>
#include <hip/hip_bf16.h>
#include <math.h>

// Problem constants (reference: T,B,H = 1024,128,512; A,K,F = 128,32,31)
#define T_DIM 1024
#define B_DIM 128
#define H_DIM 512
#define A_DIM 128
#define K_DIM 32
#define F_DIM 31

// Workspace layout (float offsets). Total = 671744 floats = 2.687 MB (proven fit).
#define WS_PQ    0              // [128][128] f32 : query @ W_q
#define WS_SCORE 16384          // [B][T] f32 : scores -> alignment (in-place)
#define WS_WKHI  147456         // [A=128][H=512] u16 : bf16 hi of W_k^T
#define WS_WKLO  180224         // [A=128][H=512] u16 : bf16 lo of W_k^T
#define WS_WCT   212992         // [A=128][32] u16 : bf16 Wcomb^T (f=31 zero-pad)
#define WS_PART  147456         // [8][B][H] f32 : context partials (aliases WKHI+)

typedef __attribute__((ext_vector_type(8)))  short bf16x8;
typedef __attribute__((ext_vector_type(16))) float f32x16;

__device__ __forceinline__ ushort f2bf(float x) {           // f32 -> bf16 RNE
  unsigned u = __float_as_uint(x);
  u += 0x7FFFu + ((u >> 16) & 1u);
  return (ushort)(u >> 16);
}
__device__ __forceinline__ float bf2f(ushort h) {
  return __uint_as_float(((unsigned)h) << 16);
}
__device__ __forceinline__ float fast_tanh(float x) {
  float xc = fminf(10.f, fmaxf(-10.f, x));
  float e2 = __expf(2.f * xc);
  return __fdividef(e2 - 1.f, e2 + 1.f);
}

// async global->LDS, 16B per lane; dest = wave-uniform base + lane*16 (m97/m104)
#define GLOAD16(gsrc, ldsdst) \
  __builtin_amdgcn_global_load_lds((const __attribute__((address_space(1))) void*)(gsrc), \
                                   (__attribute__((address_space(3))) void*)(ldsdst), 16, 0, 0)

// ---------------------------------------------------------------------------
// Prep: pq[b][a] f32; WcombT bf16 [a][32] (conv x W_loc fused, f=31 zeroed);
// W_k -> transposed bf16 hi/lo [a][h].
// ---------------------------------------------------------------------------
__global__ __launch_bounds__(256) void prep_kernel(
    const float* __restrict__ query, const float* __restrict__ conv_filter,
    const float* __restrict__ W_loc, const float* __restrict__ W_q,
    const float* __restrict__ W_k, float* __restrict__ ws)
{
  int blk = blockIdx.x, tid = threadIdx.x;
  if (blk < 128) {                       // pq for b = blk
    __shared__ float red[256];
    int a = tid & 127, half = tid >> 7;
    const float* q = query + blk * H_DIM + half * 256;
    const float* w = W_q + (size_t)(half * 256) * A_DIM + a;
    float s = 0.f;
    #pragma unroll 8
    for (int h = 0; h < 256; ++h) s = fmaf(q[h], w[(size_t)h * A_DIM], s);
    red[tid] = s;
    __syncthreads();
    if (tid < 128) ws[WS_PQ + blk * A_DIM + tid] = red[tid] + red[tid + 128];
  } else if (blk == 128) {               // WcombT bf16
    ushort* wct = (ushort*)(ws + WS_WCT);
    for (int it = 0; it < 16; ++it) {
      int e = tid + it * 256;            // 0..4095
      int f = e >> 7, a = e & 127;
      float s = 0.f;
      if (f < F_DIM) {
        #pragma unroll
        for (int k = 0; k < K_DIM; ++k)
          s += conv_filter[k * F_DIM + f] * W_loc[k * A_DIM + a];
      }
      wct[a * 32 + f] = f2bf(s);
    }
  } else {                               // W_k -> bf16 hi/lo transposed
    ushort* wkhi = (ushort*)(ws + WS_WKHI);
    ushort* wklo = (ushort*)(ws + WS_WKLO);
    int h0 = (blk - 129) * 16;
    int a = tid & 127, hh = tid >> 7;
    #pragma unroll
    for (int j = 0; j < 8; ++j) {
      int h = h0 + hh * 8 + j;
      float x = W_k[(size_t)h * A_DIM + a];
      ushort hi = f2bf(x);
      float lo = x - bf2f(hi);
      wkhi[a * H_DIM + h] = hi;
      wklo[a * H_DIM + h] = f2bf(lo);
    }
  }
}

// ---------------------------------------------------------------------------
// Score kernel: block = 32 rows (1 t x 32 b) x 128 a. The block's enc tile is
// one CONTIGUOUS 64KB slab, staged f32 via async global_load_lds with a
// both-sides XOR swizzle (kb ^= row<<4) for conflict-free per-row ds_reads.
// bf16 hi/lo split done consumer-side; B = W_k^T bf16 hi/lo from L2 into regs
// (no B LDS, no extra barriers). Location term = 17th K-step MFMA from global
// prev. Wave w owns a-cols [w*32, w*32+32); cross-wave reduce via 512B LDS.
// ---------------------------------------------------------------------------
__global__ __launch_bounds__(256, 2) void score_kernel(
    const float* __restrict__ enc, const float* __restrict__ ws_f,
    const float* __restrict__ prev, const float* __restrict__ vvec,
    float* __restrict__ score)
{
  __shared__ float smS[16384];         // [32 rows][512 k] f32, XOR-swizzled
  __shared__ float smR[128];           // [4 waves][32 rows] epilogue partials

  const ushort* wkhi = (const ushort*)(ws_f + WS_WKHI);
  const ushort* wklo = (const ushort*)(ws_f + WS_WKLO);
  const ushort* wct  = (const ushort*)(ws_f + WS_WCT);
  const float*  pq   = ws_f + WS_PQ;

  const int tid = threadIdx.x;
  const int t0 = blockIdx.x >> 2;
  const int b0 = (blockIdx.x & 3) << 5;
  const int lane = tid & 63, w = tid >> 6;
  const int l31 = lane & 31, g = lane >> 5;

  // ---- stage the contiguous 64KB enc slab (source pre-swizzled, G21) ----
  const size_t gbase = ((size_t)t0 * B_DIM + b0) * H_DIM;
  #pragma unroll
  for (int i = 0; i < 16; ++i) {
    int ldsoff = (w << 14) + (i << 10);          // wave-uniform dest byte base
    int d = ldsoff + (lane << 4);                // this lane's dest byte
    int row = d >> 11;
    int src = (row << 11) + ((d & 2047) ^ (row << 4));
    GLOAD16(enc + gbase + (src >> 2), &smS[ldsoff >> 2]);
  }
  asm volatile("s_waitcnt vmcnt(0)" ::: "memory");
  __syncthreads();

  // ---- K loop: 32 MFMA k-steps of 16 over H=512 ----
  const int a_idx = (w << 5) + l31;
  const ushort* bhp = wkhi + (size_t)a_idx * H_DIM + (g << 3);
  const ushort* blp = wklo + (size_t)a_idx * H_DIM + (g << 3);
  const int rswz = l31 << 4;
  const int rbase = l31 << 11;

  f32x16 acc = (f32x16)(0.f);
  #pragma unroll 8
  for (int kk = 0; kk < 32; ++kk) {
    int a0 = rbase + (((kk << 6) + (g << 5)) ^ rswz);
    float4 x0 = *(const float4*)((const char*)smS + a0);
    float4 x1 = *(const float4*)((const char*)smS + (a0 ^ 16));
    float xs[8] = {x0.x, x0.y, x0.z, x0.w, x1.x, x1.y, x1.z, x1.w};
    bf16x8 ah, al;
    #pragma unroll
    for (int e = 0; e < 8; ++e) {
      ushort hi = f2bf(xs[e]);
      ah[e] = (short)hi;
      al[e] = (short)f2bf(xs[e] - bf2f(hi));
    }
    bf16x8 bh = *(const bf16x8*)(bhp + (kk << 4));
    bf16x8 bl = *(const bf16x8*)(blp + (kk << 4));
    acc = __builtin_amdgcn_mfma_f32_32x32x16_bf16(ah, bh, acc, 0, 0, 0);
    acc = __builtin_amdgcn_mfma_f32_32x32x16_bf16(ah, bl, acc, 0, 0, 0);
    acc = __builtin_amdgcn_mfma_f32_32x32x16_bf16(al, bh, acc, 0, 0, 0);
  }

  // ---- K-step 17: location term (shifted prev @ Wcomb^T), from global ----
  #pragma unroll
  for (int kt = 0; kt < 2; ++kt) {
    bf16x8 ap;
    #pragma unroll
    for (int e = 0; e < 8; ++e) {
      int f = (kt << 4) + (g << 3) + e;
      int t = t0 - 15 + f;
      float pv = (f < F_DIM && t >= 0 && t < T_DIM) ? prev[t * B_DIM + b0 + l31] : 0.f;
      ap[e] = (short)f2bf(pv);
    }
    bf16x8 bp = *(const bf16x8*)(wct + (a_idx << 5) + (kt << 4) + (g << 3));
    acc = __builtin_amdgcn_mfma_f32_32x32x16_bf16(ap, bp, acc, 0, 0, 0);
  }

  // ---- epilogue: + pq, tanh, dot v, 32-lane + cross-wave reduce ----
  float va = vvec[a_idx];
  #pragma unroll
  for (int reg = 0; reg < 16; ++reg) {
    int row = (reg & 3) + ((reg >> 2) << 3) + (g << 2);   // m74/m101 C/D map
    float u = acc[reg] + pq[(b0 + row) * A_DIM + a_idx];
    float p = fast_tanh(u) * va;
    p += __shfl_xor(p, 1); p += __shfl_xor(p, 2); p += __shfl_xor(p, 4);
    p += __shfl_xor(p, 8); p += __shfl_xor(p, 16);
    if (l31 == 0) smR[(w << 5) + row] = p;
  }
  __syncthreads();
  if (tid < 32) {
    float sc = smR[tid] + smR[32 + tid] + smR[64 + tid] + smR[96 + tid];
    score[(size_t)(b0 + tid) * T_DIM + t0] = sc;           // [B][T]
  }
}

// ---------------------------------------------------------------------------
// Softmax over t per batch b; alignment in-place ([B][T]) + d_out ([T][B]).
// ---------------------------------------------------------------------------
__global__ __launch_bounds__(256) void softmax_kernel(
    float* __restrict__ score, float* __restrict__ out_align)
{
  __shared__ float red[8];
  int b = blockIdx.x, tid = threadIdx.x;
  float v0[4];
  #pragma unroll
  for (int i = 0; i < 4; ++i) v0[i] = score[b * T_DIM + tid + i * 256];
  float m = fmaxf(fmaxf(v0[0], v0[1]), fmaxf(v0[2], v0[3]));
  #pragma unroll
  for (int off = 1; off < 64; off <<= 1) m = fmaxf(m, __shfl_xor(m, off));
  if ((tid & 63) == 0) red[tid >> 6] = m;
  __syncthreads();
  m = fmaxf(fmaxf(red[0], red[1]), fmaxf(red[2], red[3]));
  float s = 0.f;
  #pragma unroll
  for (int i = 0; i < 4; ++i) { v0[i] = expf(v0[i] - m); s += v0[i]; }
  #pragma unroll
  for (int off = 1; off < 64; off <<= 1) s += __shfl_xor(s, off);
  if ((tid & 63) == 0) red[4 + (tid >> 6)] = s;
  __syncthreads();
  float inv = 1.f / (red[4] + red[5] + red[6] + red[7]);
  #pragma unroll
  for (int i = 0; i < 4; ++i) {
    float a = v0[i] * inv;
    int t = tid + i * 256;
    score[b * T_DIM + t] = a;
    out_align[t * B_DIM + b] = a;
  }
}

// ---------------------------------------------------------------------------
// Context: block = (t-chunk of 128, 2 b's). Per t the block reads 4KB
// CONTIGUOUS (256 threads x float4); 4 reg accumulators/thread; 8-deep
// unrolled independent loads. Single-writer partial[tc][b][h] (deterministic).
// ---------------------------------------------------------------------------
__global__ __launch_bounds__(256) void context_partial(
    const float* __restrict__ enc, const float* __restrict__ align_bt,
    float* __restrict__ partial)
{
  int tq = blockIdx.x >> 6;            // 0..7  : 128 t's each
  int bg = blockIdx.x & 63;            // 0..63 : 2 b's each
  int bi = threadIdx.x >> 7;
  int b  = (bg << 1) + bi;
  int h0 = (threadIdx.x & 127) << 2;
  const float* ap = align_bt + (size_t)b * T_DIM + (tq << 7);
  const float* ep = enc + ((size_t)(tq << 7) * B_DIM + b) * H_DIM + h0;
  const size_t ts = (size_t)B_DIM * H_DIM;
  float4 acc = make_float4(0.f, 0.f, 0.f, 0.f);
  for (int t = 0; t < 128; t += 8) {
    #pragma unroll
    for (int u2 = 0; u2 < 8; ++u2) {
      float a = ap[t + u2];
      float4 e = *(const float4*)(ep + (size_t)(t + u2) * ts);
      acc.x = fmaf(a, e.x, acc.x);
      acc.y = fmaf(a, e.y, acc.y);
      acc.z = fmaf(a, e.z, acc.z);
      acc.w = fmaf(a, e.w, acc.w);
    }
  }
  *(float4*)(partial + ((size_t)tq * B_DIM + b) * H_DIM + h0) = acc;
}

__global__ __launch_bounds__(256) void context_reduce(
    const float* __restrict__ partial, float* __restrict__ ctx)
{
  int idx = blockIdx.x * 256 + threadIdx.x;   // 0..65535 = b*512+h
  float s = 0.f;
  #pragma unroll
  for (int tc = 0; tc < 8; ++tc) s += partial[tc * (B_DIM * H_DIM) + idx];
  ctx[idx] = s;
}

// ---------------------------------------------------------------------------
extern "C" void kernel_launch(void* const* d_in, const int* in_sizes, int n_in,
                              void* d_out, int out_size, void* d_ws, size_t ws_size,
                              hipStream_t stream)
{
  const float* enc   = (const float*)d_in[0];  // [T,B,H]
  const float* query = (const float*)d_in[1];  // [B,H]
  const float* prev  = (const float*)d_in[2];  // [T,B]
  const float* filt  = (const float*)d_in[3];  // [K,1,F]
  const float* wloc  = (const float*)d_in[4];  // [K,A]
  const float* wq    = (const float*)d_in[5];  // [H,A]
  const float* wkp   = (const float*)d_in[6];  // [H,A]
  const float* vvec  = (const float*)d_in[7];  // [A]
  float* out = (float*)d_out;                  // context [B,H] then alignment [T,B]
  float* ws  = (float*)d_ws;

  prep_kernel<<<161, 256, 0, stream>>>(query, filt, wloc, wq, wkp, ws);
  score_kernel<<<4096, 256, 0, stream>>>(enc, ws, prev, vvec, ws + WS_SCORE);
  softmax_kernel<<<128, 256, 0, stream>>>(ws + WS_SCORE, out + B_DIM * H_DIM);
  context_partial<<<512, 256, 0, stream>>>(enc, ws + WS_SCORE, ws + WS_PART);
  context_reduce<<<256, 256, 0, stream>>>(ws + WS_PART, out);
}